// Round 1
// baseline (135.411 us; speedup 1.0000x reference)
//
#include <hip/hip_runtime.h>

// LIF scan: z [B=32, T=1024, H=512] fp32 -> out [32,1024,512] fp32
//   V_t = 0.9*V_{t-1} + z[:,t-1,:] - (V_{t-1} > 1)          (exact fp32 op order)
//   out[:,t,:] = (V_t > 1) ? 1 : 0,  out[:,0,:] = 0
// One thread per (b,h) chain: 16384 threads = 256 waves. Memory-bound stream;
// P=31 register prefetch pipeline (31*33 = 1023 steps exactly) keeps ~2 MB of
// loads in flight chip-wide to hide HBM latency at 1 wave/CU occupancy.

#define LIF_B 32
#define LIF_T 1024
#define LIF_H 512
#define LIF_S 1023   // time steps
#define LIF_P 31     // prefetch depth; 31 * 33 == 1023

__global__ __launch_bounds__(64) void lif_kernel(const float* __restrict__ z,
                                                 float* __restrict__ out) {
    const int n = blockIdx.x * blockDim.x + threadIdx.x;   // 0..16383
    const int b = n >> 9;                                  // n / 512
    const int h = n & (LIF_H - 1);                         // n % 512
    const int base = b * (LIF_T * LIF_H) + h;              // element index of z[b,0,h]

    out[base] = 0.0f;                                      // t = 0 row stays zero

    float buf[LIF_P];
#pragma unroll
    for (int i = 0; i < LIF_P; ++i)
        buf[i] = z[base + i * LIF_H];

    float V = 0.0f;
    int t = 0;
    // 32 full blocks with prefetch (covers t = 0..991, prefetches up to t=1022)
    for (int blk = 0; blk < 32; ++blk) {
#pragma unroll
        for (int i = 0; i < LIF_P; ++i) {
            const float zv = buf[i];
            buf[i] = z[base + (t + LIF_P) * LIF_H];        // prefetch t+31
            // exact reference op order: (0.9*V + z) - reset ; no FMA contraction
            const float v0 = __fadd_rn(__fmul_rn(0.9f, V), zv);
            const float Vn = (V > 1.0f) ? __fsub_rn(v0, 1.0f) : v0;
            out[base + (t + 1) * LIF_H] = (Vn > 1.0f) ? 1.0f : 0.0f;
            V = Vn;
            ++t;
        }
    }
    // tail block, no prefetch (t = 992..1022)
#pragma unroll
    for (int i = 0; i < LIF_P; ++i) {
        const float zv = buf[i];
        const float v0 = __fadd_rn(__fmul_rn(0.9f, V), zv);
        const float Vn = (V > 1.0f) ? __fsub_rn(v0, 1.0f) : v0;
        out[base + (t + 1) * LIF_H] = (Vn > 1.0f) ? 1.0f : 0.0f;
        V = Vn;
        ++t;
    }
}

extern "C" void kernel_launch(void* const* d_in, const int* in_sizes, int n_in,
                              void* d_out, int out_size, void* d_ws, size_t ws_size,
                              hipStream_t stream) {
    const float* z = (const float*)d_in[0];
    float* out = (float*)d_out;
    const int total = LIF_B * LIF_H;                       // 16384 chains
    dim3 block(64);
    dim3 grid(total / 64);                                 // 256 blocks -> all 256 CUs
    hipLaunchKernelGGL(lif_kernel, grid, block, 0, stream, z, out);
}